// Round 6
// baseline (641.763 us; speedup 1.0000x reference)
//
#include <hip/hip_runtime.h>
#include <hip/hip_fp16.h>

#define TPB 256
#define EPB 4096     // edges per partition block
#define CSHIFT 8     // coarse bucket = 256 nodes
#define AGG_BLOCKS 2048   // persistent-wave grid for the pull kernels

typedef _Float16 half8 __attribute__((ext_vector_type(8)));
typedef float    f32x4 __attribute__((ext_vector_type(4)));

// ---------------- device-scope grid barrier (all blocks co-resident by construction) ----------------
// 391 blocks x 42KB LDS -> 3 blocks/CU -> capacity 768 >= 391. Arrive with release,
// spin with acquire loads; __threadfence flushes/invalidates across XCD L2s.

__device__ __forceinline__ void grid_barrier(int* bar, int id, int nblk) {
    __syncthreads();
    if (threadIdx.x == 0) {
        __threadfence();   // release: push this block's writes to the coherence point
        __hip_atomic_fetch_add(&bar[id], 1, __ATOMIC_RELEASE, __HIP_MEMORY_SCOPE_AGENT);
        while (__hip_atomic_load(&bar[id], __ATOMIC_ACQUIRE, __HIP_MEMORY_SCOPE_AGENT) < nblk)
            __builtin_amdgcn_s_sleep(4);
        __threadfence();   // acquire: discard stale lines
    }
    __syncthreads();
}

// in-block exclusive scan of a[0..len) (len<=512), 2 entries/thread; total -> *total_out
__device__ __forceinline__ void scan512_global(int* a, int len, int* ls, int* total_out) {
    const int t = threadIdx.x;
    const int i0 = 2 * t, i1 = 2 * t + 1;
    int v0 = (i0 < len) ? a[i0] : 0;
    int v1 = (i1 < len) ? a[i1] : 0;
    ls[t] = v0 + v1;
    __syncthreads();
    for (int off = 1; off < 256; off <<= 1) {
        int xv = (t >= off) ? ls[t - off] : 0;
        __syncthreads();
        ls[t] += xv;
        __syncthreads();
    }
    int excl = (t == 0) ? 0 : ls[t - 1];
    if (i0 < len) a[i0] = excl;
    if (i1 < len) a[i1] = excl + v0;
    if (t == 255 && total_out) *total_out = ls[255];
    __syncthreads();
}

// ---------------- MEGA kernel: wprep + hist + scan + partition + finalize + layer-1 GEMM ----------------
// Grid = max(NBC, NBLK_E) = 391 blocks. Phases separated by device-scope grid barriers.
// pairs entries are PACKED 32-bit: (dst_local << 17) | src   (N=100000 < 2^17)

__global__ __launch_bounds__(256) void mega_kernel(
    const float* __restrict__ W1, const float* __restrict__ W2,
    _Float16* __restrict__ wf1g, _Float16* __restrict__ wf2g,
    const int* __restrict__ src, const int* __restrict__ dst,
    int* __restrict__ hist, int* __restrict__ chunk_sums,
    int* __restrict__ pairs, int* __restrict__ row_ptr,
    float* __restrict__ dinv, int* __restrict__ csr_src,
    const float* __restrict__ X, __half* __restrict__ hs1,
    int* __restrict__ bar,
    int n, int e, int nbc, int nblk, int ntiles) {

    __shared__ __align__(16) char smem[42496];   // 41.5 KB, reused per phase
    const int t = threadIdx.x;
    const int b = blockIdx.x;
    const int G = gridDim.x;

    // ======== P1: per-edge-block histogram (+ W fragment prep on blocks 0/1) ========
    if (b < nblk) {
        int* hs = (int*)smem;
        for (int i = t; i < nbc; i += 256) hs[i] = 0;
        __syncthreads();
        const int e0  = b * EPB;
        const int lim = min(e0 + EPB, e);
        for (int i = e0 + t; i < lim; i += 256)
            atomicAdd(&hs[dst[i] >> CSHIFT], 1);
        __syncthreads();
        for (int bk = t; bk < nbc; bk += 256)
            hist[bk * nblk + b] = hs[bk];
    }
    if (b == 0) {            // W1 -> MFMA fragment blob
        for (int f = t; f < 8 * 4 * 64; f += 256) {
            int c = f >> 8, i = (f >> 6) & 3, lane = f & 63;
            int quad = lane >> 4, nn = lane & 15;
            const float* wp = W1 + (size_t)(i * 32 + quad * 8) * 128 + c * 16 + nn;
            half8 hv;
#pragma unroll
            for (int j = 0; j < 8; ++j) hv[j] = (_Float16)wp[(size_t)j * 128];
            ((half8*)wf1g)[f] = hv;
        }
    } else if (b == 1) {     // W2 -> MFMA fragment blob
        for (int f = t; f < 4 * 4 * 64; f += 256) {
            int c = f >> 8, i = (f >> 6) & 3, lane = f & 63;
            int quad = lane >> 4, nn = lane & 15;
            const float* wp = W2 + (size_t)(i * 32 + quad * 8) * 64 + c * 16 + nn;
            half8 hv;
#pragma unroll
            for (int j = 0; j < 8; ++j) hv[j] = (_Float16)wp[(size_t)j * 64];
            ((half8*)wf2g)[f] = hv;
        }
    }
    grid_barrier(bar, 0, G);

    // ======== P2a: exclusive scan within each bucket row (nblk entries/row) ========
    if (b < nbc)
        scan512_global(hist + (size_t)b * nblk, nblk, (int*)smem, &chunk_sums[b]);
    grid_barrier(bar, 1, G);

    // ======== P2b: exclusive scan of the nbc row totals (block 0) ========
    if (b == 0)
        scan512_global(chunk_sums, nbc, (int*)smem, nullptr);
    grid_barrier(bar, 2, G);

    // ======== P3: deterministic counting partition ========
    if (b < nblk) {
        int*  hs     = (int*)smem;          // 512
        int*  lscan  = hs + 512;            // 512
        int*  lfill  = lscan + 512;         // 512
        int*  base_s = lfill + 512;         // 512
        int*  ls     = base_s + 512;        // 256
        int2* sp     = (int2*)(ls + 256);   // 4096 (32 KB)
        for (int i = t; i < nbc; i += 256) { hs[i] = 0; lfill[i] = 0; }
        __syncthreads();
        const int e0  = b * EPB;
        const int lim = min(e0 + EPB, e);
        for (int i = e0 + t; i < lim; i += 256)
            atomicAdd(&hs[dst[i] >> CSHIFT], 1);
        __syncthreads();
        int v0 = (2 * t     < nbc) ? hs[2 * t]     : 0;
        int v1 = (2 * t + 1 < nbc) ? hs[2 * t + 1] : 0;
        ls[t] = v0 + v1;
        __syncthreads();
        for (int off = 1; off < 256; off <<= 1) {
            int xv = (t >= off) ? ls[t - off] : 0;
            __syncthreads();
            ls[t] += xv;
            __syncthreads();
        }
        int excl = (t == 0) ? 0 : ls[t - 1];
        if (2 * t     < nbc) lscan[2 * t]     = excl;
        if (2 * t + 1 < nbc) lscan[2 * t + 1] = excl + v0;
        for (int bk = t; bk < nbc; bk += 256)
            base_s[bk] = hist[(size_t)bk * nblk + b] + chunk_sums[bk];
        __syncthreads();
        for (int i = e0 + t; i < lim; i += 256) {
            int d = dst[i];
            int bk = d >> CSHIFT;
            int r = atomicAdd(&lfill[bk], 1);
            sp[lscan[bk] + r] = make_int2(src[i], d);
        }
        __syncthreads();
        const int cnt = lim - e0;
        for (int i = t; i < cnt; i += 256) {
            int2 pr = sp[i];
            int  bk = pr.y >> CSHIFT;
            pairs[base_s[bk] + (i - lscan[bk])] = pr.x | ((pr.y & 255) << 17);
        }
    }
    grid_barrier(bar, 3, G);

    // ======== P4: per-bucket finalize (row_ptr, dinv, csr_src) ========
    if (b < nbc) {
        int* cnt_s = (int*)smem;       // 256
        int* fill  = cnt_s + 256;      // 256
        int* ls    = fill + 256;       // 256
        const int nb0 = b << CSHIFT;
        const int r0  = hist[(size_t)b * nblk] + chunk_sums[b];
        int r1 = e;
        if (b + 1 < nbc) r1 = hist[(size_t)(b + 1) * nblk] + chunk_sums[b + 1];
        cnt_s[t] = 0;
        __syncthreads();
        for (int i = r0 + t; i < r1; i += 256)
            atomicAdd(&cnt_s[pairs[i] >> 17], 1);
        __syncthreads();
        int c = cnt_s[t];
        ls[t] = c;
        __syncthreads();
        for (int off = 1; off < 256; off <<= 1) {
            int xv = (t >= off) ? ls[t - off] : 0;
            __syncthreads();
            ls[t] += xv;
            __syncthreads();
        }
        int excl = (t == 0) ? 0 : ls[t - 1];
        int node = nb0 + t;
        if (node < n) {
            row_ptr[node] = r0 + excl;
            dinv[node]    = rsqrtf((float)(c + 1));   // +1 self-loop
        }
        fill[t] = r0 + excl;
        __syncthreads();
        for (int i = r0 + t; i < r1; i += 256) {
            int pr = pairs[i];
            int p  = atomicAdd(&fill[pr >> 17], 1);
            csr_src[p] = pr & 0x1FFFF;
        }
        if (b == 0 && t == 0) row_ptr[n] = e;
    }
    grid_barrier(bar, 4, G);

    // ======== P5: layer-1 GEMM, grid-stride over 64-row tiles ========
    {
        _Float16* Wf = (_Float16*)smem;     // 32 KB
        const uint4* wb = (const uint4*)wf1g;
        for (int f = t; f < 8 * 4 * 64; f += 256)
            ((uint4*)Wf)[f] = wb[f];
        __syncthreads();
        const int wave = t >> 6, lane = t & 63;
        const int quad = lane >> 4, n16 = lane & 15;
        for (int tile = b; tile < ntiles; tile += G) {
            const long rowbase = (long)tile * 64 + wave * 16;
            long arow = rowbase + n16;
            const float4* xr = (const float4*)(X + (size_t)(arow < n ? arow : 0) * 128);
            half8 a[4];
#pragma unroll
            for (int i = 0; i < 4; ++i) {
                float4 x0 = xr[i * 8 + quad * 2];
                float4 x1 = xr[i * 8 + quad * 2 + 1];
                half8 hv;
                hv[0] = (_Float16)x0.x; hv[1] = (_Float16)x0.y;
                hv[2] = (_Float16)x0.z; hv[3] = (_Float16)x0.w;
                hv[4] = (_Float16)x1.x; hv[5] = (_Float16)x1.y;
                hv[6] = (_Float16)x1.z; hv[7] = (_Float16)x1.w;
                a[i] = hv;
            }
            float dv[4];
#pragma unroll
            for (int r = 0; r < 4; ++r) {
                long orow = rowbase + quad * 4 + r;
                dv[r] = (orow < n) ? dinv[orow] : 0.f;
            }
            for (int c = 0; c < 8; ++c) {
                f32x4 acc = {0.f, 0.f, 0.f, 0.f};
#pragma unroll
                for (int i = 0; i < 4; ++i) {
                    half8 bb = ((const half8*)Wf)[(c * 4 + i) * 64 + lane];
                    acc = __builtin_amdgcn_mfma_f32_16x16x32_f16(a[i], bb, acc, 0, 0, 0);
                }
#pragma unroll
                for (int r = 0; r < 4; ++r) {
                    long orow = rowbase + quad * 4 + r;
                    if (orow < n)
                        hs1[orow * 128 + c * 16 + n16] = __float2half(acc[r] * dv[r]);
                }
            }
        }
    }
}

// ---------------- dense transform via MFMA (layer 2): HS(fp16) = dinv[row] * relu(X) @ W ----------------

template <int M, bool RELU, typename XT>
__global__ __launch_bounds__(256) void gemm_mfma_kernel(const XT* __restrict__ X,
                                                        const _Float16* __restrict__ Wfg,
                                                        const float* __restrict__ dinv,
                                                        __half* __restrict__ H, int nrows) {
    constexpr int NC = M / 16;
    __shared__ __align__(16) _Float16 Wf[NC * 4 * 64 * 8];

    const int tid = threadIdx.x;
    const uint4* wb = (const uint4*)Wfg;
    for (int f = tid; f < NC * 4 * 64; f += 256)
        ((uint4*)Wf)[f] = wb[f];
    __syncthreads();

    const int  wave = tid >> 6, lane = tid & 63;
    const int  quad = lane >> 4, n16 = lane & 15;
    const long rowbase = (long)blockIdx.x * 64 + wave * 16;

    long arow = rowbase + n16;
    const XT* xrow = X + (size_t)(arow < nrows ? arow : 0) * 128;
    half8 a[4];
    if constexpr (sizeof(XT) == 4) {
        const float4* xr = (const float4*)xrow;
#pragma unroll
        for (int i = 0; i < 4; ++i) {
            float4 x0 = xr[i * 8 + quad * 2];
            float4 x1 = xr[i * 8 + quad * 2 + 1];
            if (RELU) {
                x0.x = fmaxf(x0.x, 0.f); x0.y = fmaxf(x0.y, 0.f);
                x0.z = fmaxf(x0.z, 0.f); x0.w = fmaxf(x0.w, 0.f);
                x1.x = fmaxf(x1.x, 0.f); x1.y = fmaxf(x1.y, 0.f);
                x1.z = fmaxf(x1.z, 0.f); x1.w = fmaxf(x1.w, 0.f);
            }
            half8 hv;
            hv[0] = (_Float16)x0.x; hv[1] = (_Float16)x0.y;
            hv[2] = (_Float16)x0.z; hv[3] = (_Float16)x0.w;
            hv[4] = (_Float16)x1.x; hv[5] = (_Float16)x1.y;
            hv[6] = (_Float16)x1.z; hv[7] = (_Float16)x1.w;
            a[i] = hv;
        }
    } else {
        const half8* xr = (const half8*)xrow;
#pragma unroll
        for (int i = 0; i < 4; ++i) {
            half8 hv = xr[i * 4 + quad];
            if (RELU) {
#pragma unroll
                for (int j = 0; j < 8; ++j)
                    hv[j] = (hv[j] > (_Float16)0) ? hv[j] : (_Float16)0;
            }
            a[i] = hv;
        }
    }

    float dv[4];
#pragma unroll
    for (int r = 0; r < 4; ++r) {
        long orow = rowbase + quad * 4 + r;
        dv[r] = (orow < nrows) ? dinv[orow] : 0.f;
    }

    for (int c = 0; c < NC; ++c) {
        f32x4 acc = {0.f, 0.f, 0.f, 0.f};
#pragma unroll
        for (int i = 0; i < 4; ++i) {
            half8 b = ((const half8*)Wf)[(c * 4 + i) * 64 + lane];
            acc = __builtin_amdgcn_mfma_f32_16x16x32_f16(a[i], b, acc, 0, 0, 0);
        }
#pragma unroll
        for (int r = 0; r < 4; ++r) {
            long orow = rowbase + quad * 4 + r;
            if (orow < nrows)
                H[orow * M + c * 16 + n16] = __float2half(acc[r] * dv[r]);
        }
    }
}

// ---------------- vectorized gather helper ----------------

__device__ __forceinline__ void add_u4(float2* a, const uint4& u) {
    float2 v0 = __half22float2(*(const __half2*)&u.x);
    float2 v1 = __half22float2(*(const __half2*)&u.y);
    float2 v2 = __half22float2(*(const __half2*)&u.z);
    float2 v3 = __half22float2(*(const __half2*)&u.w);
    a[0].x += v0.x; a[0].y += v0.y;
    a[1].x += v1.x; a[1].y += v1.y;
    a[2].x += v2.x; a[2].y += v2.y;
    a[3].x += v3.x; a[3].y += v3.y;
}

// ---------------- pull aggregation layer 1 (unchanged from R5) ----------------

__global__ __launch_bounds__(TPB) void agg_pull128_kernel(const __half* __restrict__ hs,
                                                          const int* __restrict__ csr_src,
                                                          const int* __restrict__ row_ptr,
                                                          const float* __restrict__ dinv,
                                                          const float* __restrict__ bias,
                                                          __half* __restrict__ out, int n) {
    const int wid  = blockIdx.x * (TPB / 64) + (threadIdx.x >> 6);
    const int NW   = gridDim.x * (TPB / 64);
    const int lane = threadIdx.x & 63;
    const int q    = lane >> 4;
    const int sl   = lane & 15;
    if (wid >= n) return;
    const uint4* up   = (const uint4*)hs;
    const uint4* upsl = up + sl;

    const float4* bp = (const float4*)bias;
    const float4 bb0 = bp[2 * sl], bb1 = bp[2 * sl + 1];

    int b0 = row_ptr[wid], e0 = row_ptr[wid + 1];
    int nA = wid + NW;
    int b1 = 0, e1 = 0;
    if (nA < n) { b1 = row_ptr[nA]; e1 = row_ptr[nA + 1]; }
    int m0 = e0 - b0; if (m0 > 64) m0 = 64;
    int idx0 = (lane < m0) ? csr_src[b0 + lane] : 0;
    uint4 self0 = make_uint4(0, 0, 0, 0);
    if (q == 0) self0 = up[(size_t)wid * 16 + sl];
    float dv0 = dinv[wid];

    for (int ni = wid; ni < n; ni += NW) {
        const int n1 = ni + NW, n2 = ni + 2 * NW;
        int b2 = 0, e2 = 0;
        if (n2 < n) { b2 = row_ptr[n2]; e2 = row_ptr[n2 + 1]; }
        int idx1 = 0; uint4 self1 = make_uint4(0, 0, 0, 0); float dv1 = 0.f;
        if (n1 < n) {
            int m1 = e1 - b1; if (m1 > 64) m1 = 64;
            idx1 = (lane < m1) ? csr_src[b1 + lane] : 0;
            if (q == 0) self1 = up[(size_t)n1 * 16 + sl];
            dv1 = dinv[n1];
        }
        int m = e0 - b0; if (m > 64) m = 64;
        int sA0 = __shfl(idx0, q);
        int sA1 = __shfl(idx0, 4 + q);
        int sA2 = __shfl(idx0, 8 + q);
        int sA3 = __shfl(idx0, 12 + q);
        int sB0 = __shfl(idx0, 16 + q);
        int sB1 = __shfl(idx0, 20 + q);
        int sB2 = __shfl(idx0, 24 + q);
        int sB3 = __shfl(idx0, 28 + q);
        uint4 uA0 = upsl[(size_t)(unsigned)sA0 * 16];
        uint4 uA1 = upsl[(size_t)(unsigned)sA1 * 16];
        uint4 uA2 = upsl[(size_t)(unsigned)sA2 * 16];
        uint4 uA3 = upsl[(size_t)(unsigned)sA3 * 16];
        uint4 uB0 = upsl[(size_t)(unsigned)sB0 * 16];
        uint4 uB1 = upsl[(size_t)(unsigned)sB1 * 16];
        uint4 uB2 = upsl[(size_t)(unsigned)sB2 * 16];
        uint4 uB3 = upsl[(size_t)(unsigned)sB3 * 16];
        float2 a0[4], a1[4];
#pragma unroll
        for (int k = 0; k < 4; ++k) { a0[k] = make_float2(0.f, 0.f); a1[k] = make_float2(0.f, 0.f); }
        if (m >= 32) {
            add_u4(a0, uA0); add_u4(a1, uA1); add_u4(a0, uA2); add_u4(a1, uA3);
            add_u4(a0, uB0); add_u4(a1, uB1); add_u4(a0, uB2); add_u4(a1, uB3);
        } else {
            if (q < m)      add_u4(a0, uA0);
            if (4 + q < m)  add_u4(a1, uA1);
            if (8 + q < m)  add_u4(a0, uA2);
            if (12 + q < m) add_u4(a1, uA3);
            if (16 + q < m) add_u4(a0, uB0);
            if (20 + q < m) add_u4(a1, uB1);
            if (24 + q < m) add_u4(a0, uB2);
            if (28 + q < m) add_u4(a1, uB3);
        }
        for (int j = 32; j < m; j += 16) {
            int s0 = __shfl(idx0, j + q);
            int s1 = __shfl(idx0, j + 4 + q);
            int s2 = __shfl(idx0, j + 8 + q);
            int s3 = __shfl(idx0, j + 12 + q);
            uint4 u0 = upsl[(size_t)(unsigned)s0 * 16];
            uint4 u1 = upsl[(size_t)(unsigned)s1 * 16];
            uint4 u2 = upsl[(size_t)(unsigned)s2 * 16];
            uint4 u3 = upsl[(size_t)(unsigned)s3 * 16];
            if (j + q < m)      add_u4(a0, u0);
            if (j + 4 + q < m)  add_u4(a1, u1);
            if (j + 8 + q < m)  add_u4(a0, u2);
            if (j + 12 + q < m) add_u4(a1, u3);
        }
        for (int base = b0 + 64; base < e0; base += 64) {
            int mm = e0 - base; if (mm > 64) mm = 64;
            int idxv = (lane < mm) ? csr_src[base + lane] : 0;
            for (int j = 0; j < mm; j += 16) {
                int s0 = __shfl(idxv, j + q);
                int s1 = __shfl(idxv, j + 4 + q);
                int s2 = __shfl(idxv, j + 8 + q);
                int s3 = __shfl(idxv, j + 12 + q);
                uint4 u0 = upsl[(size_t)(unsigned)s0 * 16];
                uint4 u1 = upsl[(size_t)(unsigned)s1 * 16];
                uint4 u2 = upsl[(size_t)(unsigned)s2 * 16];
                uint4 u3 = upsl[(size_t)(unsigned)s3 * 16];
                if (j + q < mm)      add_u4(a0, u0);
                if (j + 4 + q < mm)  add_u4(a1, u1);
                if (j + 8 + q < mm)  add_u4(a0, u2);
                if (j + 12 + q < mm) add_u4(a1, u3);
            }
        }
#pragma unroll
        for (int k = 0; k < 4; ++k) { a0[k].x += a1[k].x; a0[k].y += a1[k].y; }
#pragma unroll
        for (int k = 0; k < 4; ++k) {
            a0[k].x += __shfl(a0[k].x, lane ^ 16);
            a0[k].y += __shfl(a0[k].y, lane ^ 16);
            a0[k].x += __shfl(a0[k].x, lane ^ 32);
            a0[k].y += __shfl(a0[k].y, lane ^ 32);
        }
        if (q == 0) {
            float2 v0 = __half22float2(*(const __half2*)&self0.x);
            float2 v1 = __half22float2(*(const __half2*)&self0.y);
            float2 v2 = __half22float2(*(const __half2*)&self0.z);
            float2 v3 = __half22float2(*(const __half2*)&self0.w);
            __half2 h0 = __floats2half2_rn(bb0.x + dv0 * (a0[0].x + v0.x),
                                           bb0.y + dv0 * (a0[0].y + v0.y));
            __half2 h1 = __floats2half2_rn(bb0.z + dv0 * (a0[1].x + v1.x),
                                           bb0.w + dv0 * (a0[1].y + v1.y));
            __half2 h2 = __floats2half2_rn(bb1.x + dv0 * (a0[2].x + v2.x),
                                           bb1.y + dv0 * (a0[2].y + v2.y));
            __half2 h3 = __floats2half2_rn(bb1.z + dv0 * (a0[3].x + v3.x),
                                           bb1.w + dv0 * (a0[3].y + v3.y));
            uint4 ov;
            ov.x = *(const unsigned*)&h0; ov.y = *(const unsigned*)&h1;
            ov.z = *(const unsigned*)&h2; ov.w = *(const unsigned*)&h3;
            ((uint4*)out)[(size_t)ni * 16 + sl] = ov;
        }
        b0 = b1; e0 = e1; idx0 = idx1; self0 = self1; dv0 = dv1;
        b1 = b2; e1 = e2;
    }
}

// ---------------- pull aggregation layer 2 (unchanged from R5) ----------------

__global__ __launch_bounds__(TPB) void agg_pull64_kernel(const __half* __restrict__ hs,
                                                         const int* __restrict__ csr_src,
                                                         const int* __restrict__ row_ptr,
                                                         const float* __restrict__ dinv,
                                                         const float* __restrict__ bias,
                                                         float* __restrict__ out, int n) {
    const int wid  = blockIdx.x * (TPB / 64) + (threadIdx.x >> 6);
    const int NW   = gridDim.x * (TPB / 64);
    const int lane = threadIdx.x & 63;
    const int q    = lane >> 3;
    const int sl   = lane & 7;
    if (wid >= n) return;
    const uint4* up   = (const uint4*)hs;
    const uint4* upsl = up + sl;

    const float4* bp = (const float4*)bias;
    const float4 bb0 = bp[2 * sl], bb1 = bp[2 * sl + 1];

    int b0 = row_ptr[wid], e0 = row_ptr[wid + 1];
    int nA = wid + NW;
    int b1 = 0, e1 = 0;
    if (nA < n) { b1 = row_ptr[nA]; e1 = row_ptr[nA + 1]; }
    int m0 = e0 - b0; if (m0 > 64) m0 = 64;
    int idx0 = (lane < m0) ? csr_src[b0 + lane] : 0;
    uint4 self0 = make_uint4(0, 0, 0, 0);
    if (q == 0) self0 = up[(size_t)wid * 8 + sl];
    float dv0 = dinv[wid];

    for (int ni = wid; ni < n; ni += NW) {
        const int n1 = ni + NW, n2 = ni + 2 * NW;
        int b2 = 0, e2 = 0;
        if (n2 < n) { b2 = row_ptr[n2]; e2 = row_ptr[n2 + 1]; }
        int idx1 = 0; uint4 self1 = make_uint4(0, 0, 0, 0); float dv1 = 0.f;
        if (n1 < n) {
            int m1 = e1 - b1; if (m1 > 64) m1 = 64;
            idx1 = (lane < m1) ? csr_src[b1 + lane] : 0;
            if (q == 0) self1 = up[(size_t)n1 * 8 + sl];
            dv1 = dinv[n1];
        }
        int m = e0 - b0; if (m > 64) m = 64;
        int sA0 = __shfl(idx0, q);
        int sA1 = __shfl(idx0, 8 + q);
        int sB0 = __shfl(idx0, 16 + q);
        int sB1 = __shfl(idx0, 24 + q);
        uint4 uA0 = upsl[(size_t)(unsigned)sA0 * 8];
        uint4 uA1 = upsl[(size_t)(unsigned)sA1 * 8];
        uint4 uB0 = upsl[(size_t)(unsigned)sB0 * 8];
        uint4 uB1 = upsl[(size_t)(unsigned)sB1 * 8];
        float2 a0[4], a1[4];
#pragma unroll
        for (int k = 0; k < 4; ++k) { a0[k] = make_float2(0.f, 0.f); a1[k] = make_float2(0.f, 0.f); }
        if (m >= 32) {
            add_u4(a0, uA0); add_u4(a1, uA1); add_u4(a0, uB0); add_u4(a1, uB1);
        } else {
            if (q < m)      add_u4(a0, uA0);
            if (8 + q < m)  add_u4(a1, uA1);
            if (16 + q < m) add_u4(a0, uB0);
            if (24 + q < m) add_u4(a1, uB1);
        }
        for (int j = 32; j < m; j += 16) {
            int s0 = __shfl(idx0, j + q);
            int s1 = __shfl(idx0, j + 8 + q);
            uint4 u0 = upsl[(size_t)(unsigned)s0 * 8];
            uint4 u1 = upsl[(size_t)(unsigned)s1 * 8];
            if (j + q < m)     add_u4(a0, u0);
            if (j + 8 + q < m) add_u4(a1, u1);
        }
        for (int base = b0 + 64; base < e0; base += 64) {
            int mm = e0 - base; if (mm > 64) mm = 64;
            int idxv = (lane < mm) ? csr_src[base + lane] : 0;
            for (int j = 0; j < mm; j += 16) {
                int s0 = __shfl(idxv, j + q);
                int s1 = __shfl(idxv, j + 8 + q);
                uint4 u0 = upsl[(size_t)(unsigned)s0 * 8];
                uint4 u1 = upsl[(size_t)(unsigned)s1 * 8];
                if (j + q < mm)     add_u4(a0, u0);
                if (j + 8 + q < mm) add_u4(a1, u1);
            }
        }
#pragma unroll
        for (int k = 0; k < 4; ++k) { a0[k].x += a1[k].x; a0[k].y += a1[k].y; }
#pragma unroll
        for (int k = 0; k < 4; ++k) {
            a0[k].x += __shfl(a0[k].x, lane ^ 8);
            a0[k].y += __shfl(a0[k].y, lane ^ 8);
            a0[k].x += __shfl(a0[k].x, lane ^ 16);
            a0[k].y += __shfl(a0[k].y, lane ^ 16);
            a0[k].x += __shfl(a0[k].x, lane ^ 32);
            a0[k].y += __shfl(a0[k].y, lane ^ 32);
        }
        if (q == 0) {
            float2 v0 = __half22float2(*(const __half2*)&self0.x);
            float2 v1 = __half22float2(*(const __half2*)&self0.y);
            float2 v2 = __half22float2(*(const __half2*)&self0.z);
            float2 v3 = __half22float2(*(const __half2*)&self0.w);
            float4 o0, o1;
            o0.x = bb0.x + dv0 * (a0[0].x + v0.x);
            o0.y = bb0.y + dv0 * (a0[0].y + v0.y);
            o0.z = bb0.z + dv0 * (a0[1].x + v1.x);
            o0.w = bb0.w + dv0 * (a0[1].y + v1.y);
            o1.x = bb1.x + dv0 * (a0[2].x + v2.x);
            o1.y = bb1.y + dv0 * (a0[2].y + v2.y);
            o1.z = bb1.z + dv0 * (a0[3].x + v3.x);
            o1.w = bb1.w + dv0 * (a0[3].y + v3.y);
            ((float4*)out)[(size_t)ni * 16 + 2 * sl]     = o0;
            ((float4*)out)[(size_t)ni * 16 + 2 * sl + 1] = o1;
        }
        b0 = b1; e0 = e1; idx0 = idx1; self0 = self1; dv0 = dv1;
        b1 = b2; e1 = e2;
    }
}

// ---------------- launcher ----------------

extern "C" void kernel_launch(void* const* d_in, const int* in_sizes, int n_in,
                              void* d_out, int out_size, void* d_ws, size_t ws_size,
                              hipStream_t stream) {
    const float* x  = (const float*)d_in[0];
    const int*   ei = (const int*)d_in[1];   // int32 on the wire
    const float* W1 = (const float*)d_in[2];
    const float* b1 = (const float*)d_in[3];
    const float* W2 = (const float*)d_in[4];
    const float* b2 = (const float*)d_in[5];
    float* out = (float*)d_out;

    const int N = in_sizes[0] / 128;   // 100000
    const int E = in_sizes[1] / 2;     // 1600000
    const int* srcv = ei;
    const int* dstv = ei + E;

    const int NBC    = (N + 255) >> CSHIFT;           // 391 coarse buckets
    const int NBLK_E = (E + EPB - 1) / EPB;           // 391 edge blocks
    const int HLEN   = NBC * NBLK_E;                  // 152,881
    const int G      = (NBC > NBLK_E) ? NBC : NBLK_E; // 391
    const int NTILES = (N + 63) / 64;                 // 1563

    // workspace layout (segments padded to 64 B; hs1/out1 16-B aligned for dwordx4)
    char* p = (char*)d_ws;
    int*      row_ptr    = (int*)p;      p += (((size_t)N + 64) * 4 + 63) & ~(size_t)63;
    int*      chunk_sums = (int*)p;      p += 4096;
    int*      hist       = (int*)p;      p += (((size_t)HLEN + 64) * 4 + 63) & ~(size_t)63;
    int*      csr_src    = (int*)p;      p += ((size_t)E * 4 + 63) & ~(size_t)63;
    float*    dinv       = (float*)p;    p += (((size_t)N + 64) * 4 + 63) & ~(size_t)63;
    _Float16* wf1g       = (_Float16*)p; p += 8 * 4 * 64 * 16;   // 32 KB blob
    _Float16* wf2g       = (_Float16*)p; p += 4 * 4 * 64 * 16;   // 16 KB blob
    int*      bar        = (int*)p;      p += 64;                // grid-barrier counters
    __half*   hs1        = (__half*)p;   p += (size_t)N * 128 * 2;
    __half*   out1       = (__half*)p;   p += (size_t)N * 128 * 2;
    int*      pairs      = (int*)out1;      // alias: out1 dead until after CSR build (E*4 <= N*256)
    __half*   hs2        = hs1;             // hs1 dead once out1 complete

    // zero the barrier counters (captured as a memset node)
    hipMemsetAsync(bar, 0, 64, stream);

    // ---- mega: wprep + CSR build + layer-1 GEMM (one launch, grid barriers inside) ----
    mega_kernel<<<G, 256, 0, stream>>>(W1, W2, wf1g, wf2g, srcv, dstv,
                                       hist, chunk_sums, pairs, row_ptr, dinv, csr_src,
                                       x, hs1, bar, N, E, NBC, NBLK_E, NTILES);

    // ---- layer 1 aggregation -> fp16 out1 ----
    agg_pull128_kernel<<<AGG_BLOCKS, TPB, 0, stream>>>(hs1, csr_src, row_ptr, dinv, b1, out1, N);

    // ---- layer 2: MFMA GEMM (fp16 in w/ fused ReLU), agg -> fp32 d_out ----
    gemm_mfma_kernel<64, true, _Float16><<<(N + 63) / 64, 256, 0, stream>>>(
        (const _Float16*)out1, wf2g, dinv, hs2, N);
    agg_pull64_kernel<<<AGG_BLOCKS, TPB, 0, stream>>>(hs2, csr_src, row_ptr, dinv, b2, out, N);
}

// Round 7
// 279.859 us; speedup vs baseline: 2.2932x; 2.2932x over previous
//
#include <hip/hip_runtime.h>
#include <hip/hip_fp16.h>

#define TPB 256
#define CHUNK 1024   // elements per scan block (256 threads x 4)
#define EPB 4096     // edges per partition block
#define CSHIFT 8     // coarse bucket = 256 nodes
#define AGG_BLOCKS 2048   // persistent-wave grid for the pull kernels

typedef _Float16 half8 __attribute__((ext_vector_type(8)));
typedef float    f32x4 __attribute__((ext_vector_type(4)));

// ---------------- two-level exclusive scan (in-place safe; chunk offsets applied by consumers) ----

__global__ __launch_bounds__(256) void scanA_kernel(const int* __restrict__ cnt,
                                                    int* __restrict__ row_ptr,
                                                    int* __restrict__ chunk_sums, int n) {
    __shared__ int ls[256];
    const int t    = threadIdx.x;
    const int base = blockIdx.x * CHUNK;
    const int idx  = base + t * 4;
    int4 v = make_int4(0, 0, 0, 0);
    if (idx + 3 < n) v = *(const int4*)(cnt + idx);
    else {
        if (idx + 0 < n) v.x = cnt[idx + 0];
        if (idx + 1 < n) v.y = cnt[idx + 1];
        if (idx + 2 < n) v.z = cnt[idx + 2];
        if (idx + 3 < n) v.w = cnt[idx + 3];
    }
    int s0 = v.x, s1 = s0 + v.y, s2 = s1 + v.z, s3 = s2 + v.w;
    ls[t] = s3;
    __syncthreads();
    for (int off = 1; off < 256; off <<= 1) {
        int xv = (t >= off) ? ls[t - off] : 0;
        __syncthreads();
        ls[t] += xv;
        __syncthreads();
    }
    int excl = (t == 0) ? 0 : ls[t - 1];
    if (idx + 0 < n) row_ptr[idx + 0] = excl;
    if (idx + 1 < n) row_ptr[idx + 1] = excl + s0;
    if (idx + 2 < n) row_ptr[idx + 2] = excl + s1;
    if (idx + 3 < n) row_ptr[idx + 3] = excl + s2;
    if (t == 255) chunk_sums[blockIdx.x] = ls[255];
}

__global__ __launch_bounds__(256) void scanB_kernel(int* __restrict__ chunk_sums, int nch) {
    __shared__ int ls[256];
    const int t = threadIdx.x;
    ls[t] = (t < nch) ? chunk_sums[t] : 0;
    __syncthreads();
    for (int off = 1; off < 256; off <<= 1) {
        int xv = (t >= off) ? ls[t - off] : 0;
        __syncthreads();
        ls[t] += xv;
        __syncthreads();
    }
    if (t < nch) chunk_sums[t] = (t == 0) ? 0 : ls[t - 1];  // exclusive
}

// ---------------- CSR build: deterministic counting partition ----------------

__global__ __launch_bounds__(256) void hist_kernel(const int* __restrict__ dst,
                                                   int* __restrict__ hist_g,
                                                   int e, int nbc, int nblk) {
    __shared__ int hs[512];
    const int t = threadIdx.x;
    for (int i = t; i < nbc; i += 256) hs[i] = 0;
    __syncthreads();
    const int e0  = blockIdx.x * EPB;
    const int lim = min(e0 + EPB, e);
    for (int i = e0 + t; i < lim; i += 256)
        atomicAdd(&hs[dst[i] >> CSHIFT], 1);
    __syncthreads();
    for (int b = t; b < nbc; b += 256)
        hist_g[b * nblk + blockIdx.x] = hs[b];
}

// pairs entries are PACKED 32-bit: (dst_local << 17) | src   (N=100000 < 2^17)
__global__ __launch_bounds__(256) void partition_kernel(const int* __restrict__ src,
                                                        const int* __restrict__ dst,
                                                        const int* __restrict__ hist_scan,
                                                        const int* __restrict__ chunk_sums,
                                                        int* __restrict__ pairs,
                                                        int e, int nbc, int nblk) {
    __shared__ int  hs[512];
    __shared__ int  lscan[512];
    __shared__ int  lfill[512];
    __shared__ int  base_s[512];
    __shared__ int  ls[256];
    __shared__ int2 sp[EPB];   // 32 KB staging
    const int t = threadIdx.x;
    for (int i = t; i < nbc; i += 256) { hs[i] = 0; lfill[i] = 0; }
    __syncthreads();
    const int e0  = blockIdx.x * EPB;
    const int lim = min(e0 + EPB, e);
    for (int i = e0 + t; i < lim; i += 256)
        atomicAdd(&hs[dst[i] >> CSHIFT], 1);
    __syncthreads();
    int v0 = (2 * t     < nbc) ? hs[2 * t]     : 0;
    int v1 = (2 * t + 1 < nbc) ? hs[2 * t + 1] : 0;
    ls[t] = v0 + v1;
    __syncthreads();
    for (int off = 1; off < 256; off <<= 1) {
        int xv = (t >= off) ? ls[t - off] : 0;
        __syncthreads();
        ls[t] += xv;
        __syncthreads();
    }
    int excl = (t == 0) ? 0 : ls[t - 1];
    if (2 * t     < nbc) lscan[2 * t]     = excl;
    if (2 * t + 1 < nbc) lscan[2 * t + 1] = excl + v0;
    for (int b = t; b < nbc; b += 256) {
        int hidx = b * nblk + blockIdx.x;
        base_s[b] = hist_scan[hidx] + chunk_sums[hidx >> 10];
    }
    __syncthreads();
    for (int i = e0 + t; i < lim; i += 256) {
        int d = dst[i];
        int b = d >> CSHIFT;
        int r = atomicAdd(&lfill[b], 1);
        sp[lscan[b] + r] = make_int2(src[i], d);
    }
    __syncthreads();
    const int cnt = lim - e0;
    for (int i = t; i < cnt; i += 256) {
        int2 pr = sp[i];
        int  b  = pr.y >> CSHIFT;
        pairs[base_s[b] + (i - lscan[b])] = pr.x | ((pr.y & 255) << 17);
    }
}

// One block per 256-node bucket: per-node count + scan in LDS, then write
// row_ptr, dinv, and place csr_src. No global atomics anywhere.
__global__ __launch_bounds__(256) void bucket_finalize_kernel(const int* __restrict__ pairs,
                                                              const int* __restrict__ hist_scan,
                                                              const int* __restrict__ chunk_sums,
                                                              int* __restrict__ row_ptr,
                                                              float* __restrict__ dinv,
                                                              int* __restrict__ csr_src,
                                                              int n, int e, int nbc, int nblk) {
    __shared__ int cnt_s[256];
    __shared__ int fill[256];
    __shared__ int ls[256];
    const int b   = blockIdx.x;
    const int nb0 = b << CSHIFT;
    const int t   = threadIdx.x;
    const int h0  = b * nblk;
    const int r0  = hist_scan[h0] + chunk_sums[h0 >> 10];      // bucket start
    int r1 = e;
    if (b + 1 < nbc) {
        const int h1 = (b + 1) * nblk;
        r1 = hist_scan[h1] + chunk_sums[h1 >> 10];
    }
    cnt_s[t] = 0;
    __syncthreads();
    for (int i = r0 + t; i < r1; i += 256)
        atomicAdd(&cnt_s[pairs[i] >> 17], 1);
    __syncthreads();
    int c = cnt_s[t];
    ls[t] = c;
    __syncthreads();
    for (int off = 1; off < 256; off <<= 1) {
        int xv = (t >= off) ? ls[t - off] : 0;
        __syncthreads();
        ls[t] += xv;
        __syncthreads();
    }
    int excl = (t == 0) ? 0 : ls[t - 1];
    int node = nb0 + t;
    if (node < n) {
        row_ptr[node] = r0 + excl;
        dinv[node]    = rsqrtf((float)(c + 1));   // +1 self-loop
    }
    fill[t] = r0 + excl;
    __syncthreads();
    for (int i = r0 + t; i < r1; i += 256) {
        int pr = pairs[i];
        int p  = atomicAdd(&fill[pr >> 17], 1);
        csr_src[p] = pr & 0x1FFFF;
    }
    if (b == 0 && t == 0) row_ptr[n] = e;
}

// ---------------- W precompute: MFMA fragment blobs (fp16), run once ----------------

__global__ __launch_bounds__(256) void wprep_kernel(const float* __restrict__ W1,
                                                    const float* __restrict__ W2,
                                                    _Float16* __restrict__ wf1g,
                                                    _Float16* __restrict__ wf2g) {
    const int tid = threadIdx.x;
    if (blockIdx.x == 0) {
        for (int f = tid; f < 8 * 4 * 64; f += 256) {
            int c    = f >> 8;
            int i    = (f >> 6) & 3;
            int lane = f & 63;
            int quad = lane >> 4, n = lane & 15;
            const float* wp = W1 + (size_t)(i * 32 + quad * 8) * 128 + c * 16 + n;
            half8 hv;
#pragma unroll
            for (int j = 0; j < 8; ++j) hv[j] = (_Float16)wp[(size_t)j * 128];
            ((half8*)wf1g)[f] = hv;
        }
    } else {
        for (int f = tid; f < 4 * 4 * 64; f += 256) {
            int c    = f >> 8;
            int i    = (f >> 6) & 3;
            int lane = f & 63;
            int quad = lane >> 4, n = lane & 15;
            const float* wp = W2 + (size_t)(i * 32 + quad * 8) * 64 + c * 16 + n;
            half8 hv;
#pragma unroll
            for (int j = 0; j < 8; ++j) hv[j] = (_Float16)wp[(size_t)j * 64];
            ((half8*)wf2g)[f] = hv;
        }
    }
}

// ---------------- dense transform via MFMA: HS(fp16) = dinv[row] * (relu?)(X) @ W ----------------
// A[m=lane&15][k=quad*8+j]; C/D: col=lane&15, row=quad*4+reg.
// W arrives as a pre-converted fragment blob -> staging is a pure uint4 copy.

template <int M, bool RELU, typename XT>
__global__ __launch_bounds__(256) void gemm_mfma_kernel(const XT* __restrict__ X,
                                                        const _Float16* __restrict__ Wfg,
                                                        const float* __restrict__ dinv,
                                                        __half* __restrict__ H, int nrows) {
    constexpr int NC = M / 16;                 // col-tiles: 8 (M=128) / 4 (M=64)
    __shared__ __align__(16) _Float16 Wf[NC * 4 * 64 * 8];   // 32 KB / 16 KB

    const int tid = threadIdx.x;
    const uint4* wb = (const uint4*)Wfg;
    for (int f = tid; f < NC * 4 * 64; f += 256)
        ((uint4*)Wf)[f] = wb[f];
    __syncthreads();

    const int  wave = tid >> 6, lane = tid & 63;
    const int  quad = lane >> 4, n16 = lane & 15;
    const long rowbase = (long)blockIdx.x * 64 + wave * 16;

    long arow = rowbase + n16;
    const XT* xrow = X + (size_t)(arow < nrows ? arow : 0) * 128;
    half8 a[4];
    if constexpr (sizeof(XT) == 4) {   // fp32 input
        const float4* xr = (const float4*)xrow;
#pragma unroll
        for (int i = 0; i < 4; ++i) {
            float4 x0 = xr[i * 8 + quad * 2];
            float4 x1 = xr[i * 8 + quad * 2 + 1];
            if (RELU) {
                x0.x = fmaxf(x0.x, 0.f); x0.y = fmaxf(x0.y, 0.f);
                x0.z = fmaxf(x0.z, 0.f); x0.w = fmaxf(x0.w, 0.f);
                x1.x = fmaxf(x1.x, 0.f); x1.y = fmaxf(x1.y, 0.f);
                x1.z = fmaxf(x1.z, 0.f); x1.w = fmaxf(x1.w, 0.f);
            }
            half8 hv;
            hv[0] = (_Float16)x0.x; hv[1] = (_Float16)x0.y;
            hv[2] = (_Float16)x0.z; hv[3] = (_Float16)x0.w;
            hv[4] = (_Float16)x1.x; hv[5] = (_Float16)x1.y;
            hv[6] = (_Float16)x1.z; hv[7] = (_Float16)x1.w;
            a[i] = hv;
        }
    } else {                           // fp16 input (out1)
        const half8* xr = (const half8*)xrow;
#pragma unroll
        for (int i = 0; i < 4; ++i) {
            half8 hv = xr[i * 4 + quad];
            if (RELU) {
#pragma unroll
                for (int j = 0; j < 8; ++j)
                    hv[j] = (hv[j] > (_Float16)0) ? hv[j] : (_Float16)0;
            }
            a[i] = hv;
        }
    }

    float dv[4];
#pragma unroll
    for (int r = 0; r < 4; ++r) {
        long orow = rowbase + quad * 4 + r;
        dv[r] = (orow < nrows) ? dinv[orow] : 0.f;
    }

    for (int c = 0; c < NC; ++c) {
        f32x4 acc = {0.f, 0.f, 0.f, 0.f};
#pragma unroll
        for (int i = 0; i < 4; ++i) {
            half8 b = ((const half8*)Wf)[(c * 4 + i) * 64 + lane];
            acc = __builtin_amdgcn_mfma_f32_16x16x32_f16(a[i], b, acc, 0, 0, 0);
        }
#pragma unroll
        for (int r = 0; r < 4; ++r) {
            long orow = rowbase + quad * 4 + r;
            if (orow < nrows)
                H[orow * M + c * 16 + n16] = __float2half(acc[r] * dv[r]);
        }
    }
}

// ---------------- vectorized gather helper: add 4 half2 (one uint4) into 4 float2 ----------------

__device__ __forceinline__ void add_u4(float2* a, const uint4& u) {
    float2 v0 = __half22float2(*(const __half2*)&u.x);
    float2 v1 = __half22float2(*(const __half2*)&u.y);
    float2 v2 = __half22float2(*(const __half2*)&u.z);
    float2 v3 = __half22float2(*(const __half2*)&u.w);
    a[0].x += v0.x; a[0].y += v0.y;
    a[1].x += v1.x; a[1].y += v1.y;
    a[2].x += v2.x; a[2].y += v2.y;
    a[3].x += v3.x; a[3].y += v3.y;
}

// ---------------- pull aggregation layer 1 (R5-proven, unchanged) ----------------

__global__ __launch_bounds__(TPB) void agg_pull128_kernel(const __half* __restrict__ hs,
                                                          const int* __restrict__ csr_src,
                                                          const int* __restrict__ row_ptr,
                                                          const float* __restrict__ dinv,
                                                          const float* __restrict__ bias,
                                                          __half* __restrict__ out, int n) {
    const int wid  = blockIdx.x * (TPB / 64) + (threadIdx.x >> 6);
    const int NW   = gridDim.x * (TPB / 64);
    const int lane = threadIdx.x & 63;
    const int q    = lane >> 4;    // edge slot 0..3
    const int sl   = lane & 15;    // 16-B chunk within the 256-B row
    if (wid >= n) return;
    const uint4* up   = (const uint4*)hs;    // row = 16 uint4
    const uint4* upsl = up + sl;

    const float4* bp = (const float4*)bias;  // loop-invariant bias
    const float4 bb0 = bp[2 * sl], bb1 = bp[2 * sl + 1];

    int b0 = row_ptr[wid], e0 = row_ptr[wid + 1];
    int nA = wid + NW;
    int b1 = 0, e1 = 0;
    if (nA < n) { b1 = row_ptr[nA]; e1 = row_ptr[nA + 1]; }
    int m0 = e0 - b0; if (m0 > 64) m0 = 64;
    int idx0 = (lane < m0) ? csr_src[b0 + lane] : 0;
    uint4 self0 = make_uint4(0, 0, 0, 0);
    if (q == 0) self0 = up[(size_t)wid * 16 + sl];
    float dv0 = dinv[wid];

    for (int ni = wid; ni < n; ni += NW) {
        const int n1 = ni + NW, n2 = ni + 2 * NW;
        int b2 = 0, e2 = 0;
        if (n2 < n) { b2 = row_ptr[n2]; e2 = row_ptr[n2 + 1]; }
        int idx1 = 0; uint4 self1 = make_uint4(0, 0, 0, 0); float dv1 = 0.f;
        if (n1 < n) {
            int m1 = e1 - b1; if (m1 > 64) m1 = 64;
            idx1 = (lane < m1) ? csr_src[b1 + lane] : 0;
            if (q == 0) self1 = up[(size_t)n1 * 16 + sl];
            dv1 = dinv[n1];
        }
        int m = e0 - b0; if (m > 64) m = 64;
        int sA0 = __shfl(idx0, q);
        int sA1 = __shfl(idx0, 4 + q);
        int sA2 = __shfl(idx0, 8 + q);
        int sA3 = __shfl(idx0, 12 + q);
        int sB0 = __shfl(idx0, 16 + q);
        int sB1 = __shfl(idx0, 20 + q);
        int sB2 = __shfl(idx0, 24 + q);
        int sB3 = __shfl(idx0, 28 + q);
        uint4 uA0 = upsl[(size_t)(unsigned)sA0 * 16];
        uint4 uA1 = upsl[(size_t)(unsigned)sA1 * 16];
        uint4 uA2 = upsl[(size_t)(unsigned)sA2 * 16];
        uint4 uA3 = upsl[(size_t)(unsigned)sA3 * 16];
        uint4 uB0 = upsl[(size_t)(unsigned)sB0 * 16];
        uint4 uB1 = upsl[(size_t)(unsigned)sB1 * 16];
        uint4 uB2 = upsl[(size_t)(unsigned)sB2 * 16];
        uint4 uB3 = upsl[(size_t)(unsigned)sB3 * 16];
        float2 a0[4], a1[4];
#pragma unroll
        for (int k = 0; k < 4; ++k) { a0[k] = make_float2(0.f, 0.f); a1[k] = make_float2(0.f, 0.f); }
        if (m >= 32) {
            add_u4(a0, uA0); add_u4(a1, uA1); add_u4(a0, uA2); add_u4(a1, uA3);
            add_u4(a0, uB0); add_u4(a1, uB1); add_u4(a0, uB2); add_u4(a1, uB3);
        } else {
            if (q < m)      add_u4(a0, uA0);
            if (4 + q < m)  add_u4(a1, uA1);
            if (8 + q < m)  add_u4(a0, uA2);
            if (12 + q < m) add_u4(a1, uA3);
            if (16 + q < m) add_u4(a0, uB0);
            if (20 + q < m) add_u4(a1, uB1);
            if (24 + q < m) add_u4(a0, uB2);
            if (28 + q < m) add_u4(a1, uB3);
        }
        for (int j = 32; j < m; j += 16) {
            int s0 = __shfl(idx0, j + q);
            int s1 = __shfl(idx0, j + 4 + q);
            int s2 = __shfl(idx0, j + 8 + q);
            int s3 = __shfl(idx0, j + 12 + q);
            uint4 u0 = upsl[(size_t)(unsigned)s0 * 16];
            uint4 u1 = upsl[(size_t)(unsigned)s1 * 16];
            uint4 u2 = upsl[(size_t)(unsigned)s2 * 16];
            uint4 u3 = upsl[(size_t)(unsigned)s3 * 16];
            if (j + q < m)      add_u4(a0, u0);
            if (j + 4 + q < m)  add_u4(a1, u1);
            if (j + 8 + q < m)  add_u4(a0, u2);
            if (j + 12 + q < m) add_u4(a1, u3);
        }
        for (int base = b0 + 64; base < e0; base += 64) {
            int mm = e0 - base; if (mm > 64) mm = 64;
            int idxv = (lane < mm) ? csr_src[base + lane] : 0;
            for (int j = 0; j < mm; j += 16) {
                int s0 = __shfl(idxv, j + q);
                int s1 = __shfl(idxv, j + 4 + q);
                int s2 = __shfl(idxv, j + 8 + q);
                int s3 = __shfl(idxv, j + 12 + q);
                uint4 u0 = upsl[(size_t)(unsigned)s0 * 16];
                uint4 u1 = upsl[(size_t)(unsigned)s1 * 16];
                uint4 u2 = upsl[(size_t)(unsigned)s2 * 16];
                uint4 u3 = upsl[(size_t)(unsigned)s3 * 16];
                if (j + q < mm)      add_u4(a0, u0);
                if (j + 4 + q < mm)  add_u4(a1, u1);
                if (j + 8 + q < mm)  add_u4(a0, u2);
                if (j + 12 + q < mm) add_u4(a1, u3);
            }
        }
#pragma unroll
        for (int k = 0; k < 4; ++k) { a0[k].x += a1[k].x; a0[k].y += a1[k].y; }
#pragma unroll
        for (int k = 0; k < 4; ++k) {
            a0[k].x += __shfl(a0[k].x, lane ^ 16);
            a0[k].y += __shfl(a0[k].y, lane ^ 16);
            a0[k].x += __shfl(a0[k].x, lane ^ 32);
            a0[k].y += __shfl(a0[k].y, lane ^ 32);
        }
        if (q == 0) {
            float2 v0 = __half22float2(*(const __half2*)&self0.x);
            float2 v1 = __half22float2(*(const __half2*)&self0.y);
            float2 v2 = __half22float2(*(const __half2*)&self0.z);
            float2 v3 = __half22float2(*(const __half2*)&self0.w);
            __half2 h0 = __floats2half2_rn(bb0.x + dv0 * (a0[0].x + v0.x),
                                           bb0.y + dv0 * (a0[0].y + v0.y));
            __half2 h1 = __floats2half2_rn(bb0.z + dv0 * (a0[1].x + v1.x),
                                           bb0.w + dv0 * (a0[1].y + v1.y));
            __half2 h2 = __floats2half2_rn(bb1.x + dv0 * (a0[2].x + v2.x),
                                           bb1.y + dv0 * (a0[2].y + v2.y));
            __half2 h3 = __floats2half2_rn(bb1.z + dv0 * (a0[3].x + v3.x),
                                           bb1.w + dv0 * (a0[3].y + v3.y));
            uint4 ov;
            ov.x = *(const unsigned*)&h0; ov.y = *(const unsigned*)&h1;
            ov.z = *(const unsigned*)&h2; ov.w = *(const unsigned*)&h3;
            ((uint4*)out)[(size_t)ni * 16 + sl] = ov;
        }
        b0 = b1; e0 = e1; idx0 = idx1; self0 = self1; dv0 = dv1;
        b1 = b2; e1 = e2;
    }
}

// ---------------- pull aggregation layer 2: out(fp32) = b + dinv_d*(hs_d + sum hs_s) ----------------
// WIDENED: 64-edge gather groups -> 8 dwordx4 gathers in flight (8 KB/wave,
// matching agg128's MLP depth). Slot q = lane>>3, chunk sl = lane&7; one load
// instruction covers 8 rows (8 edges). deg<=64 handled entirely by the first
// group; deg>64 takes the generic path.

__global__ __launch_bounds__(TPB) void agg_pull64_kernel(const __half* __restrict__ hs,
                                                         const int* __restrict__ csr_src,
                                                         const int* __restrict__ row_ptr,
                                                         const float* __restrict__ dinv,
                                                         const float* __restrict__ bias,
                                                         float* __restrict__ out, int n) {
    const int wid  = blockIdx.x * (TPB / 64) + (threadIdx.x >> 6);
    const int NW   = gridDim.x * (TPB / 64);
    const int lane = threadIdx.x & 63;
    const int q    = lane >> 3;    // edge slot 0..7
    const int sl   = lane & 7;     // 16-B chunk within the 128-B row
    if (wid >= n) return;
    const uint4* up   = (const uint4*)hs;    // row = 8 uint4
    const uint4* upsl = up + sl;

    const float4* bp = (const float4*)bias;
    const float4 bb0 = bp[2 * sl], bb1 = bp[2 * sl + 1];

    int b0 = row_ptr[wid], e0 = row_ptr[wid + 1];
    int nA = wid + NW;
    int b1 = 0, e1 = 0;
    if (nA < n) { b1 = row_ptr[nA]; e1 = row_ptr[nA + 1]; }
    int m0 = e0 - b0; if (m0 > 64) m0 = 64;
    int idx0 = (lane < m0) ? csr_src[b0 + lane] : 0;
    uint4 self0 = make_uint4(0, 0, 0, 0);
    if (q == 0) self0 = up[(size_t)wid * 8 + sl];
    float dv0 = dinv[wid];

    for (int ni = wid; ni < n; ni += NW) {
        const int n1 = ni + NW, n2 = ni + 2 * NW;
        int b2 = 0, e2 = 0;
        if (n2 < n) { b2 = row_ptr[n2]; e2 = row_ptr[n2 + 1]; }
        int idx1 = 0; uint4 self1 = make_uint4(0, 0, 0, 0); float dv1 = 0.f;
        if (n1 < n) {
            int m1 = e1 - b1; if (m1 > 64) m1 = 64;
            idx1 = (lane < m1) ? csr_src[b1 + lane] : 0;
            if (q == 0) self1 = up[(size_t)n1 * 8 + sl];
            dv1 = dinv[n1];
        }
        // ---- issue all 8 gathers for node i (full 64-edge window) ----
        int m = e0 - b0; if (m > 64) m = 64;
        int s0 = __shfl(idx0, q);
        int s1 = __shfl(idx0, 8 + q);
        int s2 = __shfl(idx0, 16 + q);
        int s3 = __shfl(idx0, 24 + q);
        int s4 = __shfl(idx0, 32 + q);
        int s5 = __shfl(idx0, 40 + q);
        int s6 = __shfl(idx0, 48 + q);
        int s7 = __shfl(idx0, 56 + q);
        uint4 u0 = upsl[(size_t)(unsigned)s0 * 8];
        uint4 u1 = upsl[(size_t)(unsigned)s1 * 8];
        uint4 u2 = upsl[(size_t)(unsigned)s2 * 8];
        uint4 u3 = upsl[(size_t)(unsigned)s3 * 8];
        uint4 u4 = upsl[(size_t)(unsigned)s4 * 8];
        uint4 u5 = upsl[(size_t)(unsigned)s5 * 8];
        uint4 u6 = upsl[(size_t)(unsigned)s6 * 8];
        uint4 u7 = upsl[(size_t)(unsigned)s7 * 8];
        // ---- consume ----
        float2 a0[4], a1[4];
#pragma unroll
        for (int k = 0; k < 4; ++k) { a0[k] = make_float2(0.f, 0.f); a1[k] = make_float2(0.f, 0.f); }
        if (m >= 64) {
            add_u4(a0, u0); add_u4(a1, u1); add_u4(a0, u2); add_u4(a1, u3);
            add_u4(a0, u4); add_u4(a1, u5); add_u4(a0, u6); add_u4(a1, u7);
        } else {
            if (q < m)      add_u4(a0, u0);
            if (8 + q < m)  add_u4(a1, u1);
            if (16 + q < m) add_u4(a0, u2);
            if (24 + q < m) add_u4(a1, u3);
            if (32 + q < m) add_u4(a0, u4);
            if (40 + q < m) add_u4(a1, u5);
            if (48 + q < m) add_u4(a0, u6);
            if (56 + q < m) add_u4(a1, u7);
        }
        // generic path: degree > 64 (essentially never)
        for (int base = b0 + 64; base < e0; base += 64) {
            int mm = e0 - base; if (mm > 64) mm = 64;
            int idxv = (lane < mm) ? csr_src[base + lane] : 0;
            for (int j = 0; j < mm; j += 16) {
                int t0 = __shfl(idxv, j + q);
                int t1 = __shfl(idxv, j + 8 + q);
                uint4 v0 = upsl[(size_t)(unsigned)t0 * 8];
                uint4 v1 = upsl[(size_t)(unsigned)t1 * 8];
                if (j + q < mm)     add_u4(a0, v0);
                if (j + 8 + q < mm) add_u4(a1, v1);
            }
        }
#pragma unroll
        for (int k = 0; k < 4; ++k) { a0[k].x += a1[k].x; a0[k].y += a1[k].y; }
        // combine across the 8 edge slots (lanes with equal sl)
#pragma unroll
        for (int k = 0; k < 4; ++k) {
            a0[k].x += __shfl(a0[k].x, lane ^ 8);
            a0[k].y += __shfl(a0[k].y, lane ^ 8);
            a0[k].x += __shfl(a0[k].x, lane ^ 16);
            a0[k].y += __shfl(a0[k].y, lane ^ 16);
            a0[k].x += __shfl(a0[k].x, lane ^ 32);
            a0[k].y += __shfl(a0[k].y, lane ^ 32);
        }
        if (q == 0) {
            float2 v0 = __half22float2(*(const __half2*)&self0.x);
            float2 v1 = __half22float2(*(const __half2*)&self0.y);
            float2 v2 = __half22float2(*(const __half2*)&self0.z);
            float2 v3 = __half22float2(*(const __half2*)&self0.w);
            float4 o0, o1;
            o0.x = bb0.x + dv0 * (a0[0].x + v0.x);
            o0.y = bb0.y + dv0 * (a0[0].y + v0.y);
            o0.z = bb0.z + dv0 * (a0[1].x + v1.x);
            o0.w = bb0.w + dv0 * (a0[1].y + v1.y);
            o1.x = bb1.x + dv0 * (a0[2].x + v2.x);
            o1.y = bb1.y + dv0 * (a0[2].y + v2.y);
            o1.z = bb1.z + dv0 * (a0[3].x + v3.x);
            o1.w = bb1.w + dv0 * (a0[3].y + v3.y);
            ((float4*)out)[(size_t)ni * 16 + 2 * sl]     = o0;
            ((float4*)out)[(size_t)ni * 16 + 2 * sl + 1] = o1;
        }
        b0 = b1; e0 = e1; idx0 = idx1; self0 = self1; dv0 = dv1;
        b1 = b2; e1 = e2;
    }
}

// ---------------- launcher ----------------

extern "C" void kernel_launch(void* const* d_in, const int* in_sizes, int n_in,
                              void* d_out, int out_size, void* d_ws, size_t ws_size,
                              hipStream_t stream) {
    const float* x  = (const float*)d_in[0];
    const int*   ei = (const int*)d_in[1];   // int32 on the wire
    const float* W1 = (const float*)d_in[2];
    const float* b1 = (const float*)d_in[3];
    const float* W2 = (const float*)d_in[4];
    const float* b2 = (const float*)d_in[5];
    float* out = (float*)d_out;

    const int N = in_sizes[0] / 128;   // 100000
    const int E = in_sizes[1] / 2;     // 1600000
    const int* srcv = ei;
    const int* dstv = ei + E;

    const int NBC    = (N + 255) >> CSHIFT;           // 391 coarse buckets
    const int NBLK_E = (E + EPB - 1) / EPB;           // 391 edge blocks
    const int HLEN   = NBC * NBLK_E;                  // 152,881
    const int NCHH   = (HLEN + CHUNK - 1) / CHUNK;    // 150

    // workspace layout (segments padded to 64 B; hs1/out1 16-B aligned for dwordx4)
    char* p = (char*)d_ws;
    int*      row_ptr    = (int*)p;      p += (((size_t)N + 64) * 4 + 63) & ~(size_t)63;
    int*      chunk_sums = (int*)p;      p += 1024;
    int*      hist       = (int*)p;      p += (((size_t)HLEN + 64) * 4 + 63) & ~(size_t)63;
    int*      csr_src    = (int*)p;      p += ((size_t)E * 4 + 63) & ~(size_t)63;
    float*    dinv       = (float*)p;    p += (((size_t)N + 64) * 4 + 63) & ~(size_t)63;
    _Float16* wf1g       = (_Float16*)p; p += 8 * 4 * 64 * 16;   // 32 KB blob
    _Float16* wf2g       = (_Float16*)p; p += 4 * 4 * 64 * 16;   // 16 KB blob
    __half*   hs1        = (__half*)p;   p += (size_t)N * 128 * 2;
    __half*   out1       = (__half*)p;   p += (size_t)N * 128 * 2;
    int*      pairs      = (int*)out1;      // alias: out1 dead until after CSR build (E*4 <= N*256)
    __half*   hs2        = hs1;             // hs1 dead once out1 complete

    // ---- W precompute (independent of everything else) ----
    wprep_kernel<<<2, 256, 0, stream>>>(W1, W2, wf1g, wf2g);

    // ---- CSR build + normalization (histogram -> scan -> partition -> finalize) ----
    hist_kernel<<<NBLK_E, 256, 0, stream>>>(dstv, hist, E, NBC, NBLK_E);
    scanA_kernel<<<NCHH, 256, 0, stream>>>(hist, hist, chunk_sums, HLEN);  // in-place safe
    scanB_kernel<<<1, 256, 0, stream>>>(chunk_sums, NCHH);
    partition_kernel<<<NBLK_E, 256, 0, stream>>>(srcv, dstv, hist, chunk_sums, pairs,
                                                 E, NBC, NBLK_E);
    bucket_finalize_kernel<<<NBC, 256, 0, stream>>>(pairs, hist, chunk_sums, row_ptr, dinv,
                                                    csr_src, N, E, NBC, NBLK_E);

    // ---- layer 1: MFMA GEMM (fp32 in, fp16 out), agg -> fp16 out1 ----
    gemm_mfma_kernel<128, false, float><<<(N + 63) / 64, 256, 0, stream>>>(x, wf1g, dinv, hs1, N);
    agg_pull128_kernel<<<AGG_BLOCKS, TPB, 0, stream>>>(hs1, csr_src, row_ptr, dinv, b1, out1, N);

    // ---- layer 2: MFMA GEMM (fp16 in w/ fused ReLU), agg -> fp32 d_out ----
    gemm_mfma_kernel<64, true, _Float16><<<(N + 63) / 64, 256, 0, stream>>>(
        (const _Float16*)out1, wf2g, dinv, hs2, N);
    agg_pull64_kernel<<<AGG_BLOCKS, TPB, 0, stream>>>(hs2, csr_src, row_ptr, dinv, b2, out, N);
}

// Round 8
// 259.826 us; speedup vs baseline: 2.4700x; 1.0771x over previous
//
#include <hip/hip_runtime.h>
#include <hip/hip_fp16.h>

#define TPB 256
#define CHUNK 1024   // elements per scan block (256 threads x 4)
#define EPB 4096     // edges per partition block
#define CSHIFT 8     // coarse bucket = 256 nodes
#define AGG_BLOCKS 2048   // persistent-wave grid for the pull kernels

typedef _Float16 half8 __attribute__((ext_vector_type(8)));
typedef float    f32x4 __attribute__((ext_vector_type(4)));

// ---------------- two-level exclusive scan (in-place safe; chunk offsets applied by consumers) ----

__global__ __launch_bounds__(256) void scanA_kernel(const int* __restrict__ cnt,
                                                    int* __restrict__ row_ptr,
                                                    int* __restrict__ chunk_sums, int n) {
    __shared__ int ls[256];
    const int t    = threadIdx.x;
    const int base = blockIdx.x * CHUNK;
    const int idx  = base + t * 4;
    int4 v = make_int4(0, 0, 0, 0);
    if (idx + 3 < n) v = *(const int4*)(cnt + idx);
    else {
        if (idx + 0 < n) v.x = cnt[idx + 0];
        if (idx + 1 < n) v.y = cnt[idx + 1];
        if (idx + 2 < n) v.z = cnt[idx + 2];
        if (idx + 3 < n) v.w = cnt[idx + 3];
    }
    int s0 = v.x, s1 = s0 + v.y, s2 = s1 + v.z, s3 = s2 + v.w;
    ls[t] = s3;
    __syncthreads();
    for (int off = 1; off < 256; off <<= 1) {
        int xv = (t >= off) ? ls[t - off] : 0;
        __syncthreads();
        ls[t] += xv;
        __syncthreads();
    }
    int excl = (t == 0) ? 0 : ls[t - 1];
    if (idx + 0 < n) row_ptr[idx + 0] = excl;
    if (idx + 1 < n) row_ptr[idx + 1] = excl + s0;
    if (idx + 2 < n) row_ptr[idx + 2] = excl + s1;
    if (idx + 3 < n) row_ptr[idx + 3] = excl + s2;
    if (t == 255) chunk_sums[blockIdx.x] = ls[255];
}

__global__ __launch_bounds__(256) void scanB_kernel(int* __restrict__ chunk_sums, int nch) {
    __shared__ int ls[256];
    const int t = threadIdx.x;
    ls[t] = (t < nch) ? chunk_sums[t] : 0;
    __syncthreads();
    for (int off = 1; off < 256; off <<= 1) {
        int xv = (t >= off) ? ls[t - off] : 0;
        __syncthreads();
        ls[t] += xv;
        __syncthreads();
    }
    if (t < nch) chunk_sums[t] = (t == 0) ? 0 : ls[t - 1];  // exclusive
}

// ---------------- CSR build: deterministic counting partition ----------------

__global__ __launch_bounds__(256) void hist_kernel(const int* __restrict__ dst,
                                                   int* __restrict__ hist_g,
                                                   int e, int nbc, int nblk) {
    __shared__ int hs[512];
    const int t = threadIdx.x;
    for (int i = t; i < nbc; i += 256) hs[i] = 0;
    __syncthreads();
    const int e0  = blockIdx.x * EPB;
    const int lim = min(e0 + EPB, e);
    for (int i = e0 + t; i < lim; i += 256)
        atomicAdd(&hs[dst[i] >> CSHIFT], 1);
    __syncthreads();
    for (int b = t; b < nbc; b += 256)
        hist_g[b * nblk + blockIdx.x] = hs[b];
}

// pairs entries are PACKED 32-bit: (dst_local << 17) | src   (N=100000 < 2^17)
__global__ __launch_bounds__(256) void partition_kernel(const int* __restrict__ src,
                                                        const int* __restrict__ dst,
                                                        const int* __restrict__ hist_scan,
                                                        const int* __restrict__ chunk_sums,
                                                        int* __restrict__ pairs,
                                                        int e, int nbc, int nblk) {
    __shared__ int  hs[512];
    __shared__ int  lscan[512];
    __shared__ int  lfill[512];
    __shared__ int  base_s[512];
    __shared__ int  ls[256];
    __shared__ int2 sp[EPB];   // 32 KB staging
    const int t = threadIdx.x;
    for (int i = t; i < nbc; i += 256) { hs[i] = 0; lfill[i] = 0; }
    __syncthreads();
    const int e0  = blockIdx.x * EPB;
    const int lim = min(e0 + EPB, e);
    for (int i = e0 + t; i < lim; i += 256)
        atomicAdd(&hs[dst[i] >> CSHIFT], 1);
    __syncthreads();
    int v0 = (2 * t     < nbc) ? hs[2 * t]     : 0;
    int v1 = (2 * t + 1 < nbc) ? hs[2 * t + 1] : 0;
    ls[t] = v0 + v1;
    __syncthreads();
    for (int off = 1; off < 256; off <<= 1) {
        int xv = (t >= off) ? ls[t - off] : 0;
        __syncthreads();
        ls[t] += xv;
        __syncthreads();
    }
    int excl = (t == 0) ? 0 : ls[t - 1];
    if (2 * t     < nbc) lscan[2 * t]     = excl;
    if (2 * t + 1 < nbc) lscan[2 * t + 1] = excl + v0;
    for (int b = t; b < nbc; b += 256) {
        int hidx = b * nblk + blockIdx.x;
        base_s[b] = hist_scan[hidx] + chunk_sums[hidx >> 10];
    }
    __syncthreads();
    for (int i = e0 + t; i < lim; i += 256) {
        int d = dst[i];
        int b = d >> CSHIFT;
        int r = atomicAdd(&lfill[b], 1);
        sp[lscan[b] + r] = make_int2(src[i], d);
    }
    __syncthreads();
    const int cnt = lim - e0;
    for (int i = t; i < cnt; i += 256) {
        int2 pr = sp[i];
        int  b  = pr.y >> CSHIFT;
        pairs[base_s[b] + (i - lscan[b])] = pr.x | ((pr.y & 255) << 17);
    }
}

// One block per 256-node bucket: per-node count + scan in LDS, then write
// row_ptr, dinv, and place csr_src. No global atomics anywhere.
__global__ __launch_bounds__(256) void bucket_finalize_kernel(const int* __restrict__ pairs,
                                                              const int* __restrict__ hist_scan,
                                                              const int* __restrict__ chunk_sums,
                                                              int* __restrict__ row_ptr,
                                                              float* __restrict__ dinv,
                                                              int* __restrict__ csr_src,
                                                              int n, int e, int nbc, int nblk) {
    __shared__ int cnt_s[256];
    __shared__ int fill[256];
    __shared__ int ls[256];
    const int b   = blockIdx.x;
    const int nb0 = b << CSHIFT;
    const int t   = threadIdx.x;
    const int h0  = b * nblk;
    const int r0  = hist_scan[h0] + chunk_sums[h0 >> 10];      // bucket start
    int r1 = e;
    if (b + 1 < nbc) {
        const int h1 = (b + 1) * nblk;
        r1 = hist_scan[h1] + chunk_sums[h1 >> 10];
    }
    cnt_s[t] = 0;
    __syncthreads();
    for (int i = r0 + t; i < r1; i += 256)
        atomicAdd(&cnt_s[pairs[i] >> 17], 1);
    __syncthreads();
    int c = cnt_s[t];
    ls[t] = c;
    __syncthreads();
    for (int off = 1; off < 256; off <<= 1) {
        int xv = (t >= off) ? ls[t - off] : 0;
        __syncthreads();
        ls[t] += xv;
        __syncthreads();
    }
    int excl = (t == 0) ? 0 : ls[t - 1];
    int node = nb0 + t;
    if (node < n) {
        row_ptr[node] = r0 + excl;
        dinv[node]    = rsqrtf((float)(c + 1));   // +1 self-loop
    }
    fill[t] = r0 + excl;
    __syncthreads();
    for (int i = r0 + t; i < r1; i += 256) {
        int pr = pairs[i];
        int p  = atomicAdd(&fill[pr >> 17], 1);
        csr_src[p] = pr & 0x1FFFF;
    }
    if (b == 0 && t == 0) row_ptr[n] = e;
}

// ---------------- W precompute: MFMA fragment blobs (fp16), run once ----------------

__global__ __launch_bounds__(256) void wprep_kernel(const float* __restrict__ W1,
                                                    const float* __restrict__ W2,
                                                    _Float16* __restrict__ wf1g,
                                                    _Float16* __restrict__ wf2g) {
    const int tid = threadIdx.x;
    if (blockIdx.x == 0) {
        for (int f = tid; f < 8 * 4 * 64; f += 256) {
            int c    = f >> 8;
            int i    = (f >> 6) & 3;
            int lane = f & 63;
            int quad = lane >> 4, n = lane & 15;
            const float* wp = W1 + (size_t)(i * 32 + quad * 8) * 128 + c * 16 + n;
            half8 hv;
#pragma unroll
            for (int j = 0; j < 8; ++j) hv[j] = (_Float16)wp[(size_t)j * 128];
            ((half8*)wf1g)[f] = hv;
        }
    } else {
        for (int f = tid; f < 4 * 4 * 64; f += 256) {
            int c    = f >> 8;
            int i    = (f >> 6) & 3;
            int lane = f & 63;
            int quad = lane >> 4, n = lane & 15;
            const float* wp = W2 + (size_t)(i * 32 + quad * 8) * 64 + c * 16 + n;
            half8 hv;
#pragma unroll
            for (int j = 0; j < 8; ++j) hv[j] = (_Float16)wp[(size_t)j * 64];
            ((half8*)wf2g)[f] = hv;
        }
    }
}

// ---------------- dense transform via MFMA: HS(fp16) = dinv[row] * (relu?)(X) @ W ----------------
// A[m=lane&15][k=quad*8+j]; C/D: col=lane&15, row=quad*4+reg.
// W arrives as a pre-converted fragment blob -> staging is a pure uint4 copy.

template <int M, bool RELU, typename XT>
__global__ __launch_bounds__(256) void gemm_mfma_kernel(const XT* __restrict__ X,
                                                        const _Float16* __restrict__ Wfg,
                                                        const float* __restrict__ dinv,
                                                        __half* __restrict__ H, int nrows) {
    constexpr int NC = M / 16;                 // col-tiles: 8 (M=128) / 4 (M=64)
    __shared__ __align__(16) _Float16 Wf[NC * 4 * 64 * 8];   // 32 KB / 16 KB

    const int tid = threadIdx.x;
    const uint4* wb = (const uint4*)Wfg;
    for (int f = tid; f < NC * 4 * 64; f += 256)
        ((uint4*)Wf)[f] = wb[f];
    __syncthreads();

    const int  wave = tid >> 6, lane = tid & 63;
    const int  quad = lane >> 4, n16 = lane & 15;
    const long rowbase = (long)blockIdx.x * 64 + wave * 16;

    long arow = rowbase + n16;
    const XT* xrow = X + (size_t)(arow < nrows ? arow : 0) * 128;
    half8 a[4];
    if constexpr (sizeof(XT) == 4) {   // fp32 input
        const float4* xr = (const float4*)xrow;
#pragma unroll
        for (int i = 0; i < 4; ++i) {
            float4 x0 = xr[i * 8 + quad * 2];
            float4 x1 = xr[i * 8 + quad * 2 + 1];
            if (RELU) {
                x0.x = fmaxf(x0.x, 0.f); x0.y = fmaxf(x0.y, 0.f);
                x0.z = fmaxf(x0.z, 0.f); x0.w = fmaxf(x0.w, 0.f);
                x1.x = fmaxf(x1.x, 0.f); x1.y = fmaxf(x1.y, 0.f);
                x1.z = fmaxf(x1.z, 0.f); x1.w = fmaxf(x1.w, 0.f);
            }
            half8 hv;
            hv[0] = (_Float16)x0.x; hv[1] = (_Float16)x0.y;
            hv[2] = (_Float16)x0.z; hv[3] = (_Float16)x0.w;
            hv[4] = (_Float16)x1.x; hv[5] = (_Float16)x1.y;
            hv[6] = (_Float16)x1.z; hv[7] = (_Float16)x1.w;
            a[i] = hv;
        }
    } else {                           // fp16 input (out1)
        const half8* xr = (const half8*)xrow;
#pragma unroll
        for (int i = 0; i < 4; ++i) {
            half8 hv = xr[i * 4 + quad];
            if (RELU) {
#pragma unroll
                for (int j = 0; j < 8; ++j)
                    hv[j] = (hv[j] > (_Float16)0) ? hv[j] : (_Float16)0;
            }
            a[i] = hv;
        }
    }

    float dv[4];
#pragma unroll
    for (int r = 0; r < 4; ++r) {
        long orow = rowbase + quad * 4 + r;
        dv[r] = (orow < nrows) ? dinv[orow] : 0.f;
    }

    for (int c = 0; c < NC; ++c) {
        f32x4 acc = {0.f, 0.f, 0.f, 0.f};
#pragma unroll
        for (int i = 0; i < 4; ++i) {
            half8 b = ((const half8*)Wf)[(c * 4 + i) * 64 + lane];
            acc = __builtin_amdgcn_mfma_f32_16x16x32_f16(a[i], b, acc, 0, 0, 0);
        }
#pragma unroll
        for (int r = 0; r < 4; ++r) {
            long orow = rowbase + quad * 4 + r;
            if (orow < nrows)
                H[orow * M + c * 16 + n16] = __float2half(acc[r] * dv[r]);
        }
    }
}

// ---------------- vectorized gather helper: add 4 half2 (one uint4) into 4 float2 ----------------

__device__ __forceinline__ void add_u4(float2* a, const uint4& u) {
    float2 v0 = __half22float2(*(const __half2*)&u.x);
    float2 v1 = __half22float2(*(const __half2*)&u.y);
    float2 v2 = __half22float2(*(const __half2*)&u.z);
    float2 v3 = __half22float2(*(const __half2*)&u.w);
    a[0].x += v0.x; a[0].y += v0.y;
    a[1].x += v1.x; a[1].y += v1.y;
    a[2].x += v2.x; a[2].y += v2.y;
    a[3].x += v3.x; a[3].y += v3.y;
}

// ---------------- pull aggregation layer 1 (R5-proven, unchanged) ----------------

__global__ __launch_bounds__(TPB) void agg_pull128_kernel(const __half* __restrict__ hs,
                                                          const int* __restrict__ csr_src,
                                                          const int* __restrict__ row_ptr,
                                                          const float* __restrict__ dinv,
                                                          const float* __restrict__ bias,
                                                          __half* __restrict__ out, int n) {
    const int wid  = blockIdx.x * (TPB / 64) + (threadIdx.x >> 6);
    const int NW   = gridDim.x * (TPB / 64);
    const int lane = threadIdx.x & 63;
    const int q    = lane >> 4;    // edge slot 0..3
    const int sl   = lane & 15;    // 16-B chunk within the 256-B row
    if (wid >= n) return;
    const uint4* up   = (const uint4*)hs;    // row = 16 uint4
    const uint4* upsl = up + sl;

    const float4* bp = (const float4*)bias;  // loop-invariant bias
    const float4 bb0 = bp[2 * sl], bb1 = bp[2 * sl + 1];

    int b0 = row_ptr[wid], e0 = row_ptr[wid + 1];
    int nA = wid + NW;
    int b1 = 0, e1 = 0;
    if (nA < n) { b1 = row_ptr[nA]; e1 = row_ptr[nA + 1]; }
    int m0 = e0 - b0; if (m0 > 64) m0 = 64;
    int idx0 = (lane < m0) ? csr_src[b0 + lane] : 0;
    uint4 self0 = make_uint4(0, 0, 0, 0);
    if (q == 0) self0 = up[(size_t)wid * 16 + sl];
    float dv0 = dinv[wid];

    for (int ni = wid; ni < n; ni += NW) {
        const int n1 = ni + NW, n2 = ni + 2 * NW;
        int b2 = 0, e2 = 0;
        if (n2 < n) { b2 = row_ptr[n2]; e2 = row_ptr[n2 + 1]; }
        int idx1 = 0; uint4 self1 = make_uint4(0, 0, 0, 0); float dv1 = 0.f;
        if (n1 < n) {
            int m1 = e1 - b1; if (m1 > 64) m1 = 64;
            idx1 = (lane < m1) ? csr_src[b1 + lane] : 0;
            if (q == 0) self1 = up[(size_t)n1 * 16 + sl];
            dv1 = dinv[n1];
        }
        int m = e0 - b0; if (m > 64) m = 64;
        int sA0 = __shfl(idx0, q);
        int sA1 = __shfl(idx0, 4 + q);
        int sA2 = __shfl(idx0, 8 + q);
        int sA3 = __shfl(idx0, 12 + q);
        int sB0 = __shfl(idx0, 16 + q);
        int sB1 = __shfl(idx0, 20 + q);
        int sB2 = __shfl(idx0, 24 + q);
        int sB3 = __shfl(idx0, 28 + q);
        uint4 uA0 = upsl[(size_t)(unsigned)sA0 * 16];
        uint4 uA1 = upsl[(size_t)(unsigned)sA1 * 16];
        uint4 uA2 = upsl[(size_t)(unsigned)sA2 * 16];
        uint4 uA3 = upsl[(size_t)(unsigned)sA3 * 16];
        uint4 uB0 = upsl[(size_t)(unsigned)sB0 * 16];
        uint4 uB1 = upsl[(size_t)(unsigned)sB1 * 16];
        uint4 uB2 = upsl[(size_t)(unsigned)sB2 * 16];
        uint4 uB3 = upsl[(size_t)(unsigned)sB3 * 16];
        float2 a0[4], a1[4];
#pragma unroll
        for (int k = 0; k < 4; ++k) { a0[k] = make_float2(0.f, 0.f); a1[k] = make_float2(0.f, 0.f); }
        if (m >= 32) {
            add_u4(a0, uA0); add_u4(a1, uA1); add_u4(a0, uA2); add_u4(a1, uA3);
            add_u4(a0, uB0); add_u4(a1, uB1); add_u4(a0, uB2); add_u4(a1, uB3);
        } else {
            if (q < m)      add_u4(a0, uA0);
            if (4 + q < m)  add_u4(a1, uA1);
            if (8 + q < m)  add_u4(a0, uA2);
            if (12 + q < m) add_u4(a1, uA3);
            if (16 + q < m) add_u4(a0, uB0);
            if (20 + q < m) add_u4(a1, uB1);
            if (24 + q < m) add_u4(a0, uB2);
            if (28 + q < m) add_u4(a1, uB3);
        }
        for (int j = 32; j < m; j += 16) {
            int s0 = __shfl(idx0, j + q);
            int s1 = __shfl(idx0, j + 4 + q);
            int s2 = __shfl(idx0, j + 8 + q);
            int s3 = __shfl(idx0, j + 12 + q);
            uint4 u0 = upsl[(size_t)(unsigned)s0 * 16];
            uint4 u1 = upsl[(size_t)(unsigned)s1 * 16];
            uint4 u2 = upsl[(size_t)(unsigned)s2 * 16];
            uint4 u3 = upsl[(size_t)(unsigned)s3 * 16];
            if (j + q < m)      add_u4(a0, u0);
            if (j + 4 + q < m)  add_u4(a1, u1);
            if (j + 8 + q < m)  add_u4(a0, u2);
            if (j + 12 + q < m) add_u4(a1, u3);
        }
        for (int base = b0 + 64; base < e0; base += 64) {
            int mm = e0 - base; if (mm > 64) mm = 64;
            int idxv = (lane < mm) ? csr_src[base + lane] : 0;
            for (int j = 0; j < mm; j += 16) {
                int s0 = __shfl(idxv, j + q);
                int s1 = __shfl(idxv, j + 4 + q);
                int s2 = __shfl(idxv, j + 8 + q);
                int s3 = __shfl(idxv, j + 12 + q);
                uint4 u0 = upsl[(size_t)(unsigned)s0 * 16];
                uint4 u1 = upsl[(size_t)(unsigned)s1 * 16];
                uint4 u2 = upsl[(size_t)(unsigned)s2 * 16];
                uint4 u3 = upsl[(size_t)(unsigned)s3 * 16];
                if (j + q < mm)      add_u4(a0, u0);
                if (j + 4 + q < mm)  add_u4(a1, u1);
                if (j + 8 + q < mm)  add_u4(a0, u2);
                if (j + 12 + q < mm) add_u4(a1, u3);
            }
        }
#pragma unroll
        for (int k = 0; k < 4; ++k) { a0[k].x += a1[k].x; a0[k].y += a1[k].y; }
#pragma unroll
        for (int k = 0; k < 4; ++k) {
            a0[k].x += __shfl(a0[k].x, lane ^ 16);
            a0[k].y += __shfl(a0[k].y, lane ^ 16);
            a0[k].x += __shfl(a0[k].x, lane ^ 32);
            a0[k].y += __shfl(a0[k].y, lane ^ 32);
        }
        if (q == 0) {
            float2 v0 = __half22float2(*(const __half2*)&self0.x);
            float2 v1 = __half22float2(*(const __half2*)&self0.y);
            float2 v2 = __half22float2(*(const __half2*)&self0.z);
            float2 v3 = __half22float2(*(const __half2*)&self0.w);
            __half2 h0 = __floats2half2_rn(bb0.x + dv0 * (a0[0].x + v0.x),
                                           bb0.y + dv0 * (a0[0].y + v0.y));
            __half2 h1 = __floats2half2_rn(bb0.z + dv0 * (a0[1].x + v1.x),
                                           bb0.w + dv0 * (a0[1].y + v1.y));
            __half2 h2 = __floats2half2_rn(bb1.x + dv0 * (a0[2].x + v2.x),
                                           bb1.y + dv0 * (a0[2].y + v2.y));
            __half2 h3 = __floats2half2_rn(bb1.z + dv0 * (a0[3].x + v3.x),
                                           bb1.w + dv0 * (a0[3].y + v3.y));
            uint4 ov;
            ov.x = *(const unsigned*)&h0; ov.y = *(const unsigned*)&h1;
            ov.z = *(const unsigned*)&h2; ov.w = *(const unsigned*)&h3;
            ((uint4*)out)[(size_t)ni * 16 + sl] = ov;
        }
        b0 = b1; e0 = e1; idx0 = idx1; self0 = self1; dv0 = dv1;
        b1 = b2; e1 = e2;
    }
}

// ---------------- pull aggregation layer 2: TWO NODES PER WAVE ----------------
// Half-wave per node: h = lane>>5 selects the node of the pair, qh = (lane>>3)&3
// gives 4 edge slots per node, sl = lane&7 the 16-B chunk of the 128-B row.
// Per pair-iteration: 8 dwordx4 gathers in flight (4 per node, all useful for
// deg<=32; P(deg>32) ~ 2e-4 -> rare tail). 2-deep meta pipeline over pairs.

__global__ __launch_bounds__(TPB) void agg_pull64_kernel(const __half* __restrict__ hs,
                                                         const int* __restrict__ csr_src,
                                                         const int* __restrict__ row_ptr,
                                                         const float* __restrict__ dinv,
                                                         const float* __restrict__ bias,
                                                         float* __restrict__ out, int n) {
    const int wid  = blockIdx.x * (TPB / 64) + (threadIdx.x >> 6);   // pair index base
    const int NW   = gridDim.x * (TPB / 64);
    const int lane = threadIdx.x & 63;
    const int h    = lane >> 5;          // which node of the pair
    const int lh   = lane & 31;          // lane within half
    const int qh   = lh >> 3;            // edge slot 0..3 within half
    const int sl   = lane & 7;           // 16-B chunk within the 128-B row
    const int hb   = h << 5;             // half base lane for shfl
    const int npairs = (n + 1) >> 1;
    if (wid >= npairs) return;
    const uint4* up   = (const uint4*)hs;    // row = 8 uint4
    const uint4* upsl = up + sl;

    const float4* bp = (const float4*)bias;
    const float4 bb0 = bp[2 * sl], bb1 = bp[2 * sl + 1];

    // prologue: state for pair wid; row_ptr for pair wid+NW
    int np0 = 2 * wid + h;
    int b0 = 0, e0 = 0;
    if (np0 < n) { b0 = row_ptr[np0]; e0 = row_ptr[np0 + 1]; }
    int pA = wid + NW;
    int b1 = 0, e1 = 0;
    {
        int npA = 2 * pA + h;
        if (pA < npairs && npA < n) { b1 = row_ptr[npA]; e1 = row_ptr[npA + 1]; }
    }
    int m0 = e0 - b0; if (m0 > 32) m0 = 32;
    int idx0 = (lh < m0) ? csr_src[b0 + lh] : 0;
    uint4 self0 = make_uint4(0, 0, 0, 0);
    if (qh == 0 && np0 < n) self0 = up[(size_t)np0 * 8 + sl];
    float dv0 = (np0 < n) ? dinv[np0] : 0.f;

    for (int pp = wid; pp < npairs; pp += NW) {
        const int p1 = pp + NW, p2 = pp + 2 * NW;
        const int np = 2 * pp + h;           // this half's node
        // stage A: row_ptr for pair i+2
        int b2 = 0, e2 = 0;
        if (p2 < npairs) {
            int np2 = 2 * p2 + h;
            if (np2 < n) { b2 = row_ptr[np2]; e2 = row_ptr[np2 + 1]; }
        }
        // stage B: csr_src/self/dinv for pair i+1
        int idx1 = 0; uint4 self1 = make_uint4(0, 0, 0, 0); float dv1 = 0.f;
        if (p1 < npairs) {
            int np1 = 2 * p1 + h;
            if (np1 < n) {
                int m1 = e1 - b1; if (m1 > 32) m1 = 32;
                idx1 = (lh < m1) ? csr_src[b1 + lh] : 0;
                if (qh == 0) self1 = up[(size_t)np1 * 8 + sl];
                dv1 = dinv[np1];
            }
        }
        // ---- issue all 8 gathers (4 per node, 32-edge window each) ----
        int m = e0 - b0; if (m > 32) m = 32;
        int s0 = __shfl(idx0, hb + qh);
        int s1 = __shfl(idx0, hb + 4 + qh);
        int s2 = __shfl(idx0, hb + 8 + qh);
        int s3 = __shfl(idx0, hb + 12 + qh);
        int s4 = __shfl(idx0, hb + 16 + qh);
        int s5 = __shfl(idx0, hb + 20 + qh);
        int s6 = __shfl(idx0, hb + 24 + qh);
        int s7 = __shfl(idx0, hb + 28 + qh);
        uint4 u0 = upsl[(size_t)(unsigned)s0 * 8];
        uint4 u1 = upsl[(size_t)(unsigned)s1 * 8];
        uint4 u2 = upsl[(size_t)(unsigned)s2 * 8];
        uint4 u3 = upsl[(size_t)(unsigned)s3 * 8];
        uint4 u4 = upsl[(size_t)(unsigned)s4 * 8];
        uint4 u5 = upsl[(size_t)(unsigned)s5 * 8];
        uint4 u6 = upsl[(size_t)(unsigned)s6 * 8];
        uint4 u7 = upsl[(size_t)(unsigned)s7 * 8];
        // ---- consume (predicated per slot; edges k*4+qh) ----
        float2 a0[4], a1[4];
#pragma unroll
        for (int k = 0; k < 4; ++k) { a0[k] = make_float2(0.f, 0.f); a1[k] = make_float2(0.f, 0.f); }
        if (m >= 32) {
            add_u4(a0, u0); add_u4(a1, u1); add_u4(a0, u2); add_u4(a1, u3);
            add_u4(a0, u4); add_u4(a1, u5); add_u4(a0, u6); add_u4(a1, u7);
        } else {
            if (qh < m)      add_u4(a0, u0);
            if (4 + qh < m)  add_u4(a1, u1);
            if (8 + qh < m)  add_u4(a0, u2);
            if (12 + qh < m) add_u4(a1, u3);
            if (16 + qh < m) add_u4(a0, u4);
            if (20 + qh < m) add_u4(a1, u5);
            if (24 + qh < m) add_u4(a0, u6);
            if (28 + qh < m) add_u4(a1, u7);
        }
        // rare tail: degree > 32 (window is 32 now)
        for (int base = b0 + 32; base < e0; base += 32) {
            int mm = e0 - base; if (mm > 32) mm = 32;
            int idxv = (lh < mm) ? csr_src[base + lh] : 0;
            for (int j = 0; j < mm; j += 8) {
                int t0 = __shfl(idxv, hb + j + qh);
                int t1 = __shfl(idxv, hb + j + 4 + qh);
                uint4 v0 = upsl[(size_t)(unsigned)t0 * 8];
                uint4 v1 = upsl[(size_t)(unsigned)t1 * 8];
                if (j + qh < mm)     add_u4(a0, v0);
                if (j + 4 + qh < mm) add_u4(a1, v1);
            }
        }
#pragma unroll
        for (int k = 0; k < 4; ++k) { a0[k].x += a1[k].x; a0[k].y += a1[k].y; }
        // combine across the 4 edge slots of this half (xor 8 / xor 16 stay in-half)
#pragma unroll
        for (int k = 0; k < 4; ++k) {
            a0[k].x += __shfl(a0[k].x, lane ^ 8);
            a0[k].y += __shfl(a0[k].y, lane ^ 8);
            a0[k].x += __shfl(a0[k].x, lane ^ 16);
            a0[k].y += __shfl(a0[k].y, lane ^ 16);
        }
        if (qh == 0 && np < n) {
            float2 v0 = __half22float2(*(const __half2*)&self0.x);
            float2 v1 = __half22float2(*(const __half2*)&self0.y);
            float2 v2 = __half22float2(*(const __half2*)&self0.z);
            float2 v3 = __half22float2(*(const __half2*)&self0.w);
            float4 o0, o1;
            o0.x = bb0.x + dv0 * (a0[0].x + v0.x);
            o0.y = bb0.y + dv0 * (a0[0].y + v0.y);
            o0.z = bb0.z + dv0 * (a0[1].x + v1.x);
            o0.w = bb0.w + dv0 * (a0[1].y + v1.y);
            o1.x = bb1.x + dv0 * (a0[2].x + v2.x);
            o1.y = bb1.y + dv0 * (a0[2].y + v2.y);
            o1.z = bb1.z + dv0 * (a0[3].x + v3.x);
            o1.w = bb1.w + dv0 * (a0[3].y + v3.y);
            ((float4*)out)[(size_t)np * 16 + 2 * sl]     = o0;
            ((float4*)out)[(size_t)np * 16 + 2 * sl + 1] = o1;
        }
        b0 = b1; e0 = e1; idx0 = idx1; self0 = self1; dv0 = dv1;
        b1 = b2; e1 = e2;
    }
}

// ---------------- launcher ----------------

extern "C" void kernel_launch(void* const* d_in, const int* in_sizes, int n_in,
                              void* d_out, int out_size, void* d_ws, size_t ws_size,
                              hipStream_t stream) {
    const float* x  = (const float*)d_in[0];
    const int*   ei = (const int*)d_in[1];   // int32 on the wire
    const float* W1 = (const float*)d_in[2];
    const float* b1 = (const float*)d_in[3];
    const float* W2 = (const float*)d_in[4];
    const float* b2 = (const float*)d_in[5];
    float* out = (float*)d_out;

    const int N = in_sizes[0] / 128;   // 100000
    const int E = in_sizes[1] / 2;     // 1600000
    const int* srcv = ei;
    const int* dstv = ei + E;

    const int NBC    = (N + 255) >> CSHIFT;           // 391 coarse buckets
    const int NBLK_E = (E + EPB - 1) / EPB;           // 391 edge blocks
    const int HLEN   = NBC * NBLK_E;                  // 152,881
    const int NCHH   = (HLEN + CHUNK - 1) / CHUNK;    // 150

    // workspace layout (segments padded to 64 B; hs1/out1 16-B aligned for dwordx4)
    char* p = (char*)d_ws;
    int*      row_ptr    = (int*)p;      p += (((size_t)N + 64) * 4 + 63) & ~(size_t)63;
    int*      chunk_sums = (int*)p;      p += 1024;
    int*      hist       = (int*)p;      p += (((size_t)HLEN + 64) * 4 + 63) & ~(size_t)63;
    int*      csr_src    = (int*)p;      p += ((size_t)E * 4 + 63) & ~(size_t)63;
    float*    dinv       = (float*)p;    p += (((size_t)N + 64) * 4 + 63) & ~(size_t)63;
    _Float16* wf1g       = (_Float16*)p; p += 8 * 4 * 64 * 16;   // 32 KB blob
    _Float16* wf2g       = (_Float16*)p; p += 4 * 4 * 64 * 16;   // 16 KB blob
    __half*   hs1        = (__half*)p;   p += (size_t)N * 128 * 2;
    __half*   out1       = (__half*)p;   p += (size_t)N * 128 * 2;
    int*      pairs      = (int*)out1;      // alias: out1 dead until after CSR build (E*4 <= N*256)
    __half*   hs2        = hs1;             // hs1 dead once out1 complete

    // ---- W precompute (independent of everything else) ----
    wprep_kernel<<<2, 256, 0, stream>>>(W1, W2, wf1g, wf2g);

    // ---- CSR build + normalization (histogram -> scan -> partition -> finalize) ----
    hist_kernel<<<NBLK_E, 256, 0, stream>>>(dstv, hist, E, NBC, NBLK_E);
    scanA_kernel<<<NCHH, 256, 0, stream>>>(hist, hist, chunk_sums, HLEN);  // in-place safe
    scanB_kernel<<<1, 256, 0, stream>>>(chunk_sums, NCHH);
    partition_kernel<<<NBLK_E, 256, 0, stream>>>(srcv, dstv, hist, chunk_sums, pairs,
                                                 E, NBC, NBLK_E);
    bucket_finalize_kernel<<<NBC, 256, 0, stream>>>(pairs, hist, chunk_sums, row_ptr, dinv,
                                                    csr_src, N, E, NBC, NBLK_E);

    // ---- layer 1: MFMA GEMM (fp32 in, fp16 out), agg -> fp16 out1 ----
    gemm_mfma_kernel<128, false, float><<<(N + 63) / 64, 256, 0, stream>>>(x, wf1g, dinv, hs1, N);
    agg_pull128_kernel<<<AGG_BLOCKS, TPB, 0, stream>>>(hs1, csr_src, row_ptr, dinv, b1, out1, N);

    // ---- layer 2: MFMA GEMM (fp16 in w/ fused ReLU), agg -> fp32 d_out ----
    gemm_mfma_kernel<64, true, _Float16><<<(N + 63) / 64, 256, 0, stream>>>(
        (const _Float16*)out1, wf2g, dinv, hs2, N);
    agg_pull64_kernel<<<AGG_BLOCKS, TPB, 0, stream>>>(hs2, csr_src, row_ptr, dinv, b2, out, N);
}